// Round 10
// baseline (193.943 us; speedup 1.0000x reference)
//
#include <hip/hip_runtime.h>
#include <hip/hip_bf16.h>
#include <math.h>

static constexpr int Dh = 128;
static constexpr int NH = 4;
static constexpr int NB = 16;
static constexpr int SS = 1024;
static constexpr float NEGF = -1e9f;
// q pre-scale: 1/sqrt(128) * log2(e)  -> softmax runs in exp2 domain
static constexpr float SCALE2 = 0.08838834764831843f * 1.4426950408889634f;

typedef short s16x8 __attribute__((ext_vector_type(8)));
typedef short s16x4 __attribute__((ext_vector_type(4)));
typedef float f32x4 __attribute__((ext_vector_type(4)));

#define MFMA32(a, b, c) __builtin_amdgcn_mfma_f32_16x16x32_bf16(a, b, c, 0, 0, 0)
// K=16 bf16 MFMA: layouts HW-validated (r9 pass, absmax identical to MFMA32 path)
#define MFMA16(a, b, c) __builtin_amdgcn_mfma_f32_16x16x16bf16_1k(a, b, c, 0, 0, 0)

__device__ inline ushort f2bf(float f) {
    union { float f; unsigned u; } v; v.f = f;
    unsigned r = v.u + 0x7FFFu + ((v.u >> 16) & 1u);
    return (ushort)(r >> 16);
}
// packed f32x2 -> bf16x2 (RNE), maps to v_cvt_pk_bf16_f32 via HIP header
__device__ inline unsigned pk2bf(float a, float b) {
    __hip_bfloat162 h = __float22bfloat162_rn(make_float2(a, b));
    union { __hip_bfloat162 h; unsigned u; } v; v.h = h;
    return v.u;
}

// ---------------- K0: fused LN partial sums + bit-mask prep ----------------
__global__ __launch_bounds__(256) void ln_mask_kernel(const float* __restrict__ x,
                                                      float* __restrict__ part,
                                                      const int* __restrict__ edge,
                                                      unsigned long long* __restrict__ mbit) {
    const int b = blockIdx.x >> 4, p = blockIdx.x & 15;
    const int tid = threadIdx.x;
    const float4* xb = (const float4*)(x + (size_t)b * SS * Dh) + p * 2048;
    float s = 0.f, ss = 0.f;
    for (int i = tid; i < 2048; i += 256) {
        float4 v = xb[i];
        s  += v.x + v.y + v.z + v.w;
        ss += v.x * v.x + v.y * v.y + v.z * v.z + v.w * v.w;
    }
    __shared__ float r1[256], r2[256];
    r1[tid] = s; r2[tid] = ss;
    __syncthreads();
    for (int off = 128; off > 0; off >>= 1) {
        if (tid < off) { r1[tid] += r1[tid + off]; r2[tid] += r2[tid + off]; }
        __syncthreads();
    }
    if (tid == 0) { part[blockIdx.x * 2] = r1[0]; part[blockIdx.x * 2 + 1] = r2[0]; }

    if (blockIdx.x < 64) {
        const int idx = blockIdx.x * 256 + tid;   // < 1024*16
        const int sr = idx >> 4, w = idx & 15;
        const int4* ep = (const int4*)(edge + (size_t)sr * SS + w * 64);
        unsigned long long m0 = 0, m1 = 0, m2 = 0, m3 = 0;
        #pragma unroll
        for (int j = 0; j < 16; ++j) {
            int4 e = ep[j];
            const int base = j * 4;
            m0 |= (e.x == 1) ? (1ull << (base + 0)) : 0ull;
            m1 |= (e.x == 2) ? (1ull << (base + 0)) : 0ull;
            m2 |= (e.x == 3) ? (1ull << (base + 0)) : 0ull;
            m3 |= (e.x == 4) ? (1ull << (base + 0)) : 0ull;
            m0 |= (e.y == 1) ? (1ull << (base + 1)) : 0ull;
            m1 |= (e.y == 2) ? (1ull << (base + 1)) : 0ull;
            m2 |= (e.y == 3) ? (1ull << (base + 1)) : 0ull;
            m3 |= (e.y == 4) ? (1ull << (base + 1)) : 0ull;
            m0 |= (e.z == 1) ? (1ull << (base + 2)) : 0ull;
            m1 |= (e.z == 2) ? (1ull << (base + 2)) : 0ull;
            m2 |= (e.z == 3) ? (1ull << (base + 2)) : 0ull;
            m3 |= (e.z == 4) ? (1ull << (base + 2)) : 0ull;
            m0 |= (e.w == 1) ? (1ull << (base + 3)) : 0ull;
            m1 |= (e.w == 2) ? (1ull << (base + 3)) : 0ull;
            m2 |= (e.w == 3) ? (1ull << (base + 3)) : 0ull;
            m3 |= (e.w == 4) ? (1ull << (base + 3)) : 0ull;
        }
        mbit[((size_t)0 * SS + sr) * 16 + w] = m0;
        mbit[((size_t)1 * SS + sr) * 16 + w] = m1;
        mbit[((size_t)2 * SS + sr) * 16 + w] = m2;
        mbit[((size_t)3 * SS + sr) * 16 + w] = m3;
    }
}

// ---------------- K1: QKV projection, bf16 MFMA (LN fused; XCD-swizzled grid) ----------------
// grid(row=128, col=12): id%8 = row%8 -> all col-blocks of a row-tile share an XCD (x reuse in L2)
__global__ __launch_bounds__(256) void qkv_mfma_kernel(const float* __restrict__ x,
                                                       const float* __restrict__ w,    // [1536][128]
                                                       const float* __restrict__ bias, // [1536]
                                                       const float* __restrict__ part, // [256][2]
                                                       ushort* __restrict__ qo,
                                                       ushort* __restrict__ ko,
                                                       ushort* __restrict__ vto) {
    __shared__ ushort smem[2 * 128 * 72];     // As/Bs; epilogue alias Rs[128][136]
    ushort* As = smem;
    ushort* Bs = smem + 128 * 72;
    ushort* Rs = smem;
    const int tid = threadIdx.x, wave = tid >> 6, lane = tid & 63;
    const int lrow = lane & 15, quad = lane >> 4;
    const int wm = wave & 1, wn = wave >> 1;
    const int row0 = blockIdx.x * 128;
    const int col0 = blockIdx.y * 128;
    const int bb = row0 >> 10;

    float s_ = 0.f, ss_ = 0.f;
    #pragma unroll
    for (int p = 0; p < 16; ++p) { s_ += part[(bb * 16 + p) * 2]; ss_ += part[(bb * 16 + p) * 2 + 1]; }
    const float invN = 1.0f / (float)(SS * Dh);
    const float mu = s_ * invN;
    const float rstd = 1.0f / sqrtf(ss_ * invN - mu * mu + 1e-5f);

    f32x4 acc[4][4];
    #pragma unroll
    for (int mi = 0; mi < 4; ++mi)
        #pragma unroll
        for (int ni = 0; ni < 4; ++ni) acc[mi][ni] = (f32x4){0.f, 0.f, 0.f, 0.f};

    for (int kk = 0; kk < 128; kk += 64) {
        if (kk) __syncthreads();
        #pragma unroll
        for (int p = 0; p < 8; ++p) {
            int slot = p * 256 + tid;
            int r = slot >> 4, c4 = (slot & 15) << 2;
            float4 v = *(const float4*)(x + (size_t)(row0 + r) * Dh + kk + c4);
            ushort4 pa;
            pa.x = f2bf((v.x - mu) * rstd); pa.y = f2bf((v.y - mu) * rstd);
            pa.z = f2bf((v.z - mu) * rstd); pa.w = f2bf((v.w - mu) * rstd);
            *(ushort4*)&As[r * 72 + c4] = pa;
            float4 wv = *(const float4*)(w + (size_t)(col0 + r) * Dh + kk + c4);
            ushort4 pb;
            pb.x = f2bf(wv.x); pb.y = f2bf(wv.y); pb.z = f2bf(wv.z); pb.w = f2bf(wv.w);
            *(ushort4*)&Bs[r * 72 + c4] = pb;
        }
        __syncthreads();
        #pragma unroll
        for (int kc = 0; kc < 2; ++kc) {
            s16x8 af[4], bf[4];
            #pragma unroll
            for (int mi = 0; mi < 4; ++mi)
                af[mi] = *(const s16x8*)&As[(wm * 64 + 16 * mi + lrow) * 72 + kc * 32 + quad * 8];
            #pragma unroll
            for (int ni = 0; ni < 4; ++ni)
                bf[ni] = *(const s16x8*)&Bs[(wn * 64 + 16 * ni + lrow) * 72 + kc * 32 + quad * 8];
            #pragma unroll
            for (int mi = 0; mi < 4; ++mi)
                #pragma unroll
                for (int ni = 0; ni < 4; ++ni)
                    acc[mi][ni] = MFMA32(af[mi], bf[ni], acc[mi][ni]);
        }
    }

    const int seg = col0 % 384, typ = seg >> 7, h = col0 / 384;
    const size_t bh = (size_t)bb * NH + h;
    const int sl_blk = row0 & 1023;
    float bia[4];
    #pragma unroll
    for (int ni = 0; ni < 4; ++ni) bia[ni] = bias[col0 + wn * 64 + 16 * ni + lrow];
    const float sc = (typ == 0) ? SCALE2 : 1.f;

    __syncthreads();
    if (typ < 2) {
        #pragma unroll
        for (int mi = 0; mi < 4; ++mi)
            #pragma unroll
            for (int ni = 0; ni < 4; ++ni)
                #pragma unroll
                for (int reg = 0; reg < 4; ++reg)
                    Rs[(wm * 64 + 16 * mi + quad * 4 + reg) * 136 + wn * 64 + 16 * ni + lrow]
                        = f2bf((acc[mi][ni][reg] + bia[ni]) * sc);
    } else {
        #pragma unroll
        for (int mi = 0; mi < 4; ++mi)
            #pragma unroll
            for (int ni = 0; ni < 4; ++ni) {
                ushort4 pk;
                pk.x = f2bf(acc[mi][ni][0] + bia[ni]);
                pk.y = f2bf(acc[mi][ni][1] + bia[ni]);
                pk.z = f2bf(acc[mi][ni][2] + bia[ni]);
                pk.w = f2bf(acc[mi][ni][3] + bia[ni]);
                *(ushort4*)&Rs[(wn * 64 + 16 * ni + lrow) * 136 + wm * 64 + 16 * mi + quad * 4] = pk;
            }
    }
    __syncthreads();

    ushort* dstb;
    int pitch;
    if (typ == 0)      { dstb = qo  + bh * SS * 128 + (size_t)sl_blk * 128; pitch = 128; }
    else if (typ == 1) { dstb = ko  + bh * SS * 128 + (size_t)sl_blk * 128; pitch = 128; }
    else               { dstb = vto + bh * (size_t)128 * SS + sl_blk;       pitch = SS;  }
    #pragma unroll
    for (int p = 0; p < 8; ++p) {
        int slot = p * 256 + tid;
        int r = slot >> 4, c8 = (slot & 15) * 8;
        *(s16x8*)&dstb[(size_t)r * pitch + c8] = *(const s16x8*)&Rs[r * 136 + c8];
    }
}

// ---------------- K2: attention; K direct-from-global; reg-local MFMA16 PV + out-proj ----------------
static constexpr int VT_LD = 72;
static constexpr int WS_LD = 136;
static constexpr int SMEM_N = 128 * WS_LD;   // 17408 ushorts = 34816 B (Vt 128*72 aliases low part)

__global__ __launch_bounds__(256, 2) void attn_fused_kernel(const ushort* __restrict__ qg_,
                                                            const ushort* __restrict__ kg_,
                                                            const ushort* __restrict__ vg_,
                                                            const unsigned long long* __restrict__ mbit,
                                                            const float* __restrict__ wo,
                                                            const float* __restrict__ bo,
                                                            float* __restrict__ out) {
    // XCD swizzle: blockIdx.x = (b,h); all 8 q-tiles of a (b,h) share id%8 -> same XCD L2
    const int bhi = blockIdx.x, qt = blockIdx.y;
    const int b = bhi >> 2, h = bhi & 3;
    const int s0 = qt * 128;
    const int tid = threadIdx.x;
    const int wave = tid >> 6, lane = tid & 63;
    const int lrow = lane & 15, quad = lane >> 4;

    __shared__ ushort smem[SMEM_N];
    ushort* Vt = smem;                 // [d][key] stride 72
    ushort* Ws = smem;                 // epilogue alias: Wo[h] bf16 [e][d] stride 136

    const size_t bh = (size_t)(b * NH + h);
    const ushort* qg = qg_ + bh * SS * 128;
    const ushort* kg = kg_ + bh * SS * 128;
    const ushort* vg = vg_ + bh * 128 * SS;
    const unsigned long long* mrow0 = mbit + ((size_t)h * SS + (s0 + 32 * wave + lrow)) * 16;
    const unsigned long long* mrow1 = mrow0 + 16 * 16;

    // Q fragments (B-operand of S^T MFMA32): n=q=lane&15, k=kc*32+quad*8+j (q pre-scaled by 1/sqrtD*log2e)
    s16x8 qf[2][4];
    #pragma unroll
    for (int g = 0; g < 2; ++g) {
        const ushort* qr = qg + (size_t)(s0 + 32 * wave + 16 * g + lrow) * 128 + quad * 8;
        #pragma unroll
        for (int kc = 0; kc < 4; ++kc) qf[g][kc] = *(const s16x8*)(qr + kc * 32);
    }

    // V staging prefetch (tile kt=0)
    s16x8 vreg[4];
    #pragma unroll
    for (int p = 0; p < 4; ++p) {
        int slot = p * 256 + tid;
        int r = slot >> 3, c = (slot & 7) * 8;
        vreg[p] = *(const s16x8*)(vg + (size_t)r * SS + c);
    }

    // O^T accumulators: q = lane&15 (== softmax state layout), d = 16*nb + quad*4 + reg
    f32x4 oacc[2][8];
    #pragma unroll
    for (int g = 0; g < 2; ++g)
        #pragma unroll
        for (int nb = 0; nb < 8; ++nb) oacc[g][nb] = (f32x4){0.f, 0.f, 0.f, 0.f};
    float m_run[2] = {-INFINITY, -INFINITY};
    float l_run[2] = {0.f, 0.f};

    const ushort* kfbase = kg + (size_t)lrow * 128 + quad * 8;

    for (int kt = 0; kt < 16; ++kt) {
        const int t0 = kt * 64;

        // K fragments straight from global (L2-hot; overlaps the barriers below)
        s16x8 kf[4][4];
        {
            const ushort* kb_ = kfbase + (size_t)t0 * 128;
            #pragma unroll
            for (int cb = 0; cb < 4; ++cb)
                #pragma unroll
                for (int kc = 0; kc < 4; ++kc)
                    kf[cb][kc] = *(const s16x8*)(kb_ + (size_t)cb * 16 * 128 + kc * 32);
        }
        unsigned long long mw0 = mrow0[kt];
        unsigned long long mw1 = mrow1[kt];

        __syncthreads();   // previous iteration's Vt readers done
        #pragma unroll
        for (int p = 0; p < 4; ++p) {
            int slot = p * 256 + tid;
            int r = slot >> 3, c = (slot & 7) * 8;
            *(s16x8*)&Vt[r * VT_LD + c] = vreg[p];
        }
        __syncthreads();

        if (kt < 15) {
            const int t1 = t0 + 64;
            #pragma unroll
            for (int p = 0; p < 4; ++p) {
                int slot = p * 256 + tid;
                int r = slot >> 3, c = (slot & 7) * 8;
                vreg[p] = *(const s16x8*)(vg + (size_t)r * SS + t1 + c);
            }
        }

        // ---- S^T = K q^T : D[m=key=16cb+quad*4+reg][n=q=lane&15] ----
        f32x4 sacc[2][4];
        #pragma unroll
        for (int g = 0; g < 2; ++g)
            #pragma unroll
            for (int cb = 0; cb < 4; ++cb) sacc[g][cb] = (f32x4){0.f, 0.f, 0.f, 0.f};
        #pragma unroll
        for (int cb = 0; cb < 4; ++cb)
            #pragma unroll
            for (int g = 0; g < 2; ++g)
                #pragma unroll
                for (int kc = 0; kc < 4; ++kc)
                    sacc[g][cb] = MFMA32(kf[cb][kc], qf[g][kc], sacc[g][cb]);

        // ---- softmax in exp2 domain (per-lane state, q=lane&15); pf == MFMA16 B-operand ----
        s16x4 pf[2][4];
        #pragma unroll
        for (int g = 0; g < 2; ++g) {
            const unsigned long long mw = g ? mw1 : mw0;
            float sv[4][4];
            float tm = -INFINITY;
            #pragma unroll
            for (int cb = 0; cb < 4; ++cb) {
                unsigned nib = (unsigned)(mw >> (16 * cb + quad * 4)) & 0xFu;
                #pragma unroll
                for (int r = 0; r < 4; ++r) {
                    sv[cb][r] = (nib & (1u << r)) ? sacc[g][cb][r] : NEGF;
                    tm = fmaxf(tm, sv[cb][r]);
                }
            }
            tm = fmaxf(tm, __shfl_xor(tm, 16));
            tm = fmaxf(tm, __shfl_xor(tm, 32));
            float mn = fmaxf(m_run[g], tm);
            float al = exp2f(m_run[g] - mn);
            float rs = 0.f;
            #pragma unroll
            for (int cb = 0; cb < 4; ++cb) {
                float p0 = exp2f(sv[cb][0] - mn);
                float p1 = exp2f(sv[cb][1] - mn);
                float p2 = exp2f(sv[cb][2] - mn);
                float p3 = exp2f(sv[cb][3] - mn);
                rs += (p0 + p1) + (p2 + p3);
                union { unsigned u[2]; s16x4 v; } pk;
                pk.u[0] = pk2bf(p0, p1);
                pk.u[1] = pk2bf(p2, p3);
                pf[g][cb] = pk.v;
            }
            rs += __shfl_xor(rs, 16);
            rs += __shfl_xor(rs, 32);
            l_run[g] = l_run[g] * al + rs;
            m_run[g] = mn;
            #pragma unroll
            for (int nb = 0; nb < 8; ++nb)
                #pragma unroll
                for (int r = 0; r < 4; ++r) oacc[g][nb][r] *= al;
        }

        // ---- O^T += V^T P^T : MFMA16, A = V^T frag (b64 LDS), B = pf (registers) ----
        #pragma unroll
        for (int nb = 0; nb < 8; ++nb) {
            #pragma unroll
            for (int kb = 0; kb < 4; ++kb) {
                s16x4 vf = *(const s16x4*)&Vt[(16 * nb + lrow) * VT_LD + kb * 16 + quad * 4];
                #pragma unroll
                for (int g = 0; g < 2; ++g)
                    oacc[g][nb] = MFMA16(vf, pf[g][kb], oacc[g][nb]);
            }
        }
    }

    // ---- fused out-projection, fully register-local O: out = (O/l) Wo^T + bo ----
    __syncthreads();                   // main-loop Vt readers done
    const float* wbase = wo + (size_t)h * Dh * Dh;
    #pragma unroll
    for (int p = 0; p < 16; ++p) {     // stage Wo[h] 128x128 fp32 -> bf16, stride 136
        int slot = p * 256 + tid;
        int r = slot >> 5, c4 = (slot & 31) << 2;
        float4 wv = *(const float4*)(wbase + (size_t)r * Dh + c4);
        ushort4 pb;
        pb.x = f2bf(wv.x); pb.y = f2bf(wv.y); pb.z = f2bf(wv.z); pb.w = f2bf(wv.w);
        *(ushort4*)&Ws[r * WS_LD + c4] = pb;
    }
    __syncthreads();

    // B-operand frags of normalized O: d = kb*16 + quad*4 + j  == oacc[g][kb] layout exactly
    s16x4 bo16[2][8];
    #pragma unroll
    for (int g = 0; g < 2; ++g) {
        float inv = 1.0f / l_run[g];
        #pragma unroll
        for (int nb = 0; nb < 8; ++nb) {
            union { unsigned u[2]; s16x4 v; } pk;
            pk.u[0] = pk2bf(oacc[g][nb][0] * inv, oacc[g][nb][1] * inv);
            pk.u[1] = pk2bf(oacc[g][nb][2] * inv, oacc[g][nb][3] * inv);
            bo16[g][nb] = pk.v;
        }
    }

    const size_t orow0 = (size_t)b * SS + s0 + 32 * wave;
    #pragma unroll
    for (int ne = 0; ne < 8; ++ne) {
        f32x4 facc[2];
        facc[0] = (f32x4){0.f, 0.f, 0.f, 0.f};
        facc[1] = (f32x4){0.f, 0.f, 0.f, 0.f};
        #pragma unroll
        for (int kb = 0; kb < 8; ++kb) {
            s16x4 wf = *(const s16x4*)&Ws[(16 * ne + lrow) * WS_LD + kb * 16 + quad * 4];
            facc[0] = MFMA16(wf, bo16[0][kb], facc[0]);
            facc[1] = MFMA16(wf, bo16[1][kb], facc[1]);
        }
        // D[m=e=16ne+quad*4+reg][n=q=lane&15]; e contiguous in reg -> float4 store
        float4 bi = *(const float4*)(bo + h * Dh + 16 * ne + quad * 4);
        #pragma unroll
        for (int g = 0; g < 2; ++g) {
            float4 o;
            o.x = facc[g][0] + bi.x;
            o.y = facc[g][1] + bi.y;
            o.z = facc[g][2] + bi.z;
            o.w = facc[g][3] + bi.w;
            *(float4*)&out[(orow0 + 16 * g + lrow) * (NH * Dh) + h * Dh + 16 * ne + quad * 4] = o;
        }
    }
}

extern "C" void kernel_launch(void* const* d_in, const int* in_sizes, int n_in,
                              void* d_out, int out_size, void* d_ws, size_t ws_size,
                              hipStream_t stream) {
    const float* x     = (const float*)d_in[0];
    const int*   edge  = (const int*)d_in[1];
    const float* w_in  = (const float*)d_in[2];
    const float* b_in  = (const float*)d_in[3];
    const float* w_out = (const float*)d_in[4];
    const float* b_out = (const float*)d_in[5];
    float* out = (float*)d_out;

    float* ws   = (float*)d_ws;
    float* part = ws;                                              // 512 floats
    unsigned long long* mbit = (unsigned long long*)(ws + 1024);   // [4][1024][16] u64 = 512 KB
    ushort* qo  = (ushort*)(mbit + (size_t)NH * SS * 16);
    const size_t QSZ = (size_t)NB * NH * SS * 128;
    ushort* ko  = qo + QSZ;
    ushort* vto = ko + QSZ;                                        // [b][h][128][s]

    ln_mask_kernel<<<256, 256, 0, stream>>>(x, part, edge, mbit);
    qkv_mfma_kernel<<<dim3(128, 12), 256, 0, stream>>>(x, w_in, b_in, part, qo, ko, vto);
    attn_fused_kernel<<<dim3(NB * NH, SS / 128), 256, 0, stream>>>(qo, ko, vto, mbit, w_out, b_out, out);
}